// Round 20
// baseline (3812.622 us; speedup 1.0000x reference)
//
#include <hip/hip_runtime.h>
#include <stdint.h>

#define NN 4096
#define BB 4
#define MROWS 16        // rows per block
#define TPB 512         // 8 waves
#define NBLK 256        // grid (1 block/CU)
#define REDS 17         // padded red row stride (dwords)
#define RING 16         // x-state ring depth
#define XSZ  (8 * NN)   // u16 elements per ring slot (8 planes x NN)

typedef __attribute__((ext_vector_type(8))) short bf16x8;   // 8 bf16 (4 regs)
typedef __attribute__((ext_vector_type(4))) float f32x4;    // MFMA C/D

// ---------- bf16 round-to-nearest-even ----------
__device__ __forceinline__ uint32_t bf16rne(float f) {
  uint32_t u = __float_as_uint(f);
  return (u + 0x7FFFu + ((u >> 16) & 1u)) >> 16;
}

// ---------- pack B fp32 -> two row-major bf16 planes (32 MB each) ----------
__global__ void pack_planes(const float* __restrict__ Br, const float* __restrict__ Bi,
                            uint4* __restrict__ Brb, uint4* __restrict__ Bib) {
  int i = blockIdx.x * blockDim.x + threadIdx.x;     // over N*N/8
  const float4* r4 = reinterpret_cast<const float4*>(Br) + (size_t)i * 2;
  const float4* m4 = reinterpret_cast<const float4*>(Bi) + (size_t)i * 2;
  float4 a0 = r4[0], a1 = r4[1];
  float4 b0 = m4[0], b1 = m4[1];
  uint4 o;
  o.x = bf16rne(a0.x) | (bf16rne(a0.y) << 16);
  o.y = bf16rne(a0.z) | (bf16rne(a0.w) << 16);
  o.z = bf16rne(a1.x) | (bf16rne(a1.y) << 16);
  o.w = bf16rne(a1.z) | (bf16rne(a1.w) << 16);
  Brb[i] = o;
  o.x = bf16rne(b0.x) | (bf16rne(b0.y) << 16);
  o.y = bf16rne(b0.z) | (bf16rne(b0.w) << 16);
  o.z = bf16rne(b1.x) | (bf16rne(b1.y) << 16);
  o.w = bf16rne(b1.z) | (bf16rne(b1.w) << 16);
  Bib[i] = o;
}

#define AST32(p, v) __hip_atomic_store((uint32_t*)(p), (v), \
                                       __ATOMIC_RELAXED, __HIP_MEMORY_SCOPE_AGENT)

// ============================================================================
// Persistent kernel, SENTINEL protocol with WIDE L2-bypass gathers.
// Ring slots poisoned 0xFFFFFFFF (bf16 NaN pair; finite x never equals it).
// Gather x_{t-1} with inline-asm global_load_dwordx4 sc0 sc1 (bypass L1/L2,
// read L3 truth — same freshness class as the r16-proven atomic path, but
// coalesced & pipelined). Validity signal IS the data: one L3 hop per step.
// Poison-check in VALU; exec-masked re-issue for straggler lanes.
// Skew <= 1 step by construction (full-slot verification); each block
// re-poisons its own 256 B segment of slot t-3 (reused 13 steps later).
// Fragment maps identical to rounds 10-19 (verified, absmax 0.0039).
// ============================================================================
__global__ __launch_bounds__(TPB, 2)
void rnn_persistent(const uint16_t* __restrict__ Brb,
                    const uint16_t* __restrict__ Bib,
                    const float* __restrict__ omega,
                    const float* __restrict__ ang,
                    uint16_t* __restrict__ xring,  // RING * XSZ u16, poisoned 0xFF
                    float* __restrict__ out,
                    int NT) {
  extern __shared__ char smem[];
  uint4* BrL = (uint4*)smem;                       // 16 rows * 512 slots = 128 KB
  float* red = (float*)(smem + 131072);            // 8*16*REDS fp32 = 8704 B

  const int tid  = threadIdx.x;
  const int w    = tid >> 6;       // 0..7, k-window of 512 nodes
  const int lane = tid & 63;
  const int al   = lane & 15;
  const int kq   = lane >> 4;
  const int row0 = blockIdx.x * MROWS;
  const int p1   = al & 7;
  const int p2   = p1 ^ 1;
  const int swz  = al & 7;
  const uint32_t smx = (al & 1) ? 0u : 0x80008000u;  // negate -xi (even cols)

  // ---- stage Br slice into LDS, swizzled: phys = row*512 + (u ^ (row&7)) ----
  for (int j = tid; j < MROWS * 512; j += TPB) {
    int row = j >> 9;
    int u   = j & 511;
    uint4 v = *(const uint4*)(Brb + (size_t)(row0 + row) * NN + u * 8);
    BrL[row * 512 + (u ^ (row & 7))] = v;
  }

  // ---- t=0: x0 = exp(i*theta); diag regs; out[0]; ring slot 0 ----
  float myval = 0.f, om = 0.f;
  int bb = 0, mm = 0, ri = 0, cc = 0;
  if (tid < 128) {
    int r = tid >> 3; cc = tid & 7;
    mm = row0 + r; bb = cc >> 1; ri = cc & 1;
    om = omega[bb * NN + mm];
    float sv, cv;
    sincosf(ang[bb * NN + mm], &sv, &cv);
    myval = ri ? sv : cv;
    if (!ri) out[bb * NN + mm] = myval;
    float s2 = __shfl(myval, (lane + 8) & 63, 64);     // partner (r+1, same c)
    if (!((tid >> 3) & 1)) {                            // even r: pack node pair
      uint32_t pk = bf16rne(myval) | (bf16rne(s2) << 16);
      AST32((uint32_t*)xring + ((cc * NN + mm) >> 1), pk);
    }
  }
  __syncthreads();                                     // BrL ready; drain t=0 stores

  const int nb = w * 512 + kq * 8;                     // lane's k-window base
  const uint16_t* birow = Bib + (size_t)(row0 + al) * NN + nb;

// wide L2/L1-bypass load (reads L3 truth; agent-fresh like atomic path)
#define GL1(DST, PTR) \
  asm volatile("global_load_dwordx4 %0, %1, off sc0 sc1" \
               : "=&v"(DST) : "v"((unsigned long long)(uintptr_t)(PTR)));

#define GDECL(S) uint4 gA##S, gB##S;
#define GISS(S)  GL1(gA##S, xp1 + (S) * 32) GL1(gB##S, xp2 + (S) * 32)
#define PCHK(S)  bad |= (gA##S.x == ~0u) | (gA##S.y == ~0u) | (gA##S.z == ~0u) | (gA##S.w == ~0u) \
                     |  (gB##S.x == ~0u) | (gB##S.y == ~0u) | (gB##S.z == ~0u) | (gB##S.w == ~0u);
#define GALL  GISS(0)  GISS(1)  GISS(2)  GISS(3)  GISS(4)  GISS(5)  GISS(6)  GISS(7) \
              GISS(8)  GISS(9)  GISS(10) GISS(11) GISS(12) GISS(13) GISS(14) GISS(15)
#define PALL  PCHK(0)  PCHK(1)  PCHK(2)  PCHK(3)  PCHK(4)  PCHK(5)  PCHK(6)  PCHK(7) \
              PCHK(8)  PCHK(9)  PCHK(10) PCHK(11) PCHK(12) PCHK(13) PCHK(14) PCHK(15)

#define SSTEPX(S) \
    { union { uint4 q; bf16x8 v; } fr, u1, u2;                                  \
      fr.q = BrL[al * 512 + (((w << 6) + ((S) << 2) + kq) ^ swz)];              \
      bf16x8 fi = *(const bf16x8*)(birow + (S) * 32);                           \
      u1.q = gA##S;                                                             \
      u2.q = gB##S;                                                             \
      u2.q.x ^= smx; u2.q.y ^= smx; u2.q.z ^= smx; u2.q.w ^= smx;               \
      accA = __builtin_amdgcn_mfma_f32_16x16x32_bf16(fr.v, u1.v, accA, 0, 0, 0);\
      accB = __builtin_amdgcn_mfma_f32_16x16x32_bf16(fi,   u2.v, accB, 0, 0, 0); }

  for (int t = 1; t < NT; ++t) {
    const uint16_t* xs  = xring + (size_t)((t - 1) & (RING - 1)) * XSZ;
    const uint16_t* xp1 = xs + p1 * NN + nb;
    const uint16_t* xp2 = xs + p2 * NN + nb;

    GDECL(0)  GDECL(1)  GDECL(2)  GDECL(3)
    GDECL(4)  GDECL(5)  GDECL(6)  GDECL(7)
    GDECL(8)  GDECL(9)  GDECL(10) GDECL(11)
    GDECL(12) GDECL(13) GDECL(14) GDECL(15)

    GALL                                             // issue all 32 wide loads
    int spin = 0;
    for (;;) {
      asm volatile("s_waitcnt vmcnt(0)" ::: "memory");
      __builtin_amdgcn_sched_barrier(0);
      uint32_t bad = 0;
      PALL
      if (!__any((int)bad)) break;
      if (++spin > (1 << 22)) break;                 // defensive cap
      if (bad) { GALL }                              // exec-masked re-issue
    }

    f32x4 accA = {0.f, 0.f, 0.f, 0.f};
    f32x4 accB = {0.f, 0.f, 0.f, 0.f};
    SSTEPX(0)  SSTEPX(1)  SSTEPX(2)  SSTEPX(3)
    SSTEPX(4)  SSTEPX(5)  SSTEPX(6)  SSTEPX(7)
    SSTEPX(8)  SSTEPX(9)  SSTEPX(10) SSTEPX(11)
    SSTEPX(12) SSTEPX(13) SSTEPX(14) SSTEPX(15)

    // ---- partial tiles -> padded LDS ----
    {
      float* rw = red + w * 16 * REDS;
      rw[(kq * 4 + 0) * REDS + al] = accA[0] + accB[0];
      rw[(kq * 4 + 1) * REDS + al] = accA[1] + accB[1];
      rw[(kq * 4 + 2) * REDS + al] = accA[2] + accB[2];
      rw[(kq * 4 + 3) * REDS + al] = accA[3] + accB[3];
    }
    __syncthreads();

    // ---- cross-wave sum + diagonal + writes (x via agent store) ----
    if (tid < 128) {
      int r = tid >> 3;
      float s = 0.f;
#pragma unroll
      for (int w2 = 0; w2 < 8; ++w2) s += red[w2 * 16 * REDS + r * REDS + cc];
      float other = __shfl_xor(myval, 1, 64);
      float xr = ri ? other : myval;
      float xi = ri ? myval : other;
      // i*omega*(xr + i*xi) = -omega*xi + i*omega*xr
      s += ri ? (om * xr) : (-om * xi);
      myval = s;                                       // fp32 diag chain in reg
      if (!ri) out[(size_t)t * (BB * NN) + bb * NN + mm] = s;
      float s2 = __shfl(s, (lane + 8) & 63, 64);       // partner (r+1, same c)
      if (!((tid >> 3) & 1)) {
        uint32_t pk = bf16rne(s) | (bf16rne(s2) << 16);
        AST32((uint32_t*)(xring + (size_t)(t & (RING - 1)) * XSZ)
              + ((cc * NN + mm) >> 1), pk);
      }
    }

    // ---- re-poison own segment of slot t-3 (safe: slot t-1 fully verified) ----
    if (t >= 3 && tid < 64) {
      uint32_t* pb = (uint32_t*)(xring + (size_t)((t - 3) & (RING - 1)) * XSZ);
      int c = tid >> 3, k = tid & 7;
      AST32(pb + c * (NN / 2) + (row0 >> 1) + k, 0xFFFFFFFFu);
    }
    __syncthreads();                                   // guard red; drain stores
  }
#undef SSTEPX
#undef PALL
#undef GALL
#undef PCHK
#undef GISS
#undef GDECL
#undef GL1
}

// ============================================================================
// Fallback (fp32 B direct, per-step launches) — only if coop launch fails.
// ============================================================================
__global__ void init_kernel(const float* __restrict__ ang,
                            float2* __restrict__ st0, float* __restrict__ out0) {
  int i = blockIdx.x * blockDim.x + threadIdx.x;
  if (i < BB * NN) {
    float s, c;
    sincosf(ang[i], &s, &c);
    st0[i] = make_float2(c, s);
    out0[i] = c;
  }
}

__global__ __launch_bounds__(1024)
void step_fb(const float* __restrict__ Brf, const float* __restrict__ Bif,
             const float* __restrict__ omega,
             const float2* __restrict__ stPrev, float2* __restrict__ stNext,
             float* __restrict__ outRe) {
  extern __shared__ float lds[];
  float* xl  = lds;
  float* xh  = lds + NN * 4;
  float* red = lds + NN * 8;
  const int tid = threadIdx.x;
#pragma unroll
  for (int k = 0; k < 8; ++k) {
    int idx = tid + k * 1024;
    int half = idx >> 12;
    int n = idx & (NN - 1);
    float2 v0 = stPrev[(half * 2) * NN + n];
    float2 v1 = stPrev[(half * 2 + 1) * NN + n];
    reinterpret_cast<float4*>(half ? xh : xl)[n] = make_float4(v0.x, v0.y, v1.x, v1.y);
  }
  __syncthreads();
  const int w = tid >> 6, lane = tid & 63, rg = w >> 2, q = w & 3;
  const int row0 = blockIdx.x * MROWS + rg * 4;
  float acc[4][8];
#pragma unroll
  for (int r = 0; r < 4; ++r)
#pragma unroll
    for (int c = 0; c < 8; ++c) acc[r][c] = 0.0f;
#define CFMA(A, BR, BI, XA, XB)                                   \
  A[0] = fmaf(BR, XA.x, A[0]); A[0] = fmaf(-BI, XA.y, A[0]);      \
  A[1] = fmaf(BR, XA.y, A[1]); A[1] = fmaf(BI, XA.x, A[1]);       \
  A[2] = fmaf(BR, XA.z, A[2]); A[2] = fmaf(-BI, XA.w, A[2]);      \
  A[3] = fmaf(BR, XA.w, A[3]); A[3] = fmaf(BI, XA.z, A[3]);       \
  A[4] = fmaf(BR, XB.x, A[4]); A[4] = fmaf(-BI, XB.y, A[4]);      \
  A[5] = fmaf(BR, XB.y, A[5]); A[5] = fmaf(BI, XB.x, A[5]);       \
  A[6] = fmaf(BR, XB.z, A[6]); A[6] = fmaf(-BI, XB.w, A[6]);      \
  A[7] = fmaf(BR, XB.w, A[7]); A[7] = fmaf(BI, XB.z, A[7]);
  for (int i4 = 0; i4 < 4; ++i4) {
    const int n0 = q * 1024 + i4 * 256 + lane * 4;
    float4 xa[4], xb[4];
#pragma unroll
    for (int j = 0; j < 4; ++j) {
      xa[j] = reinterpret_cast<const float4*>(xl)[n0 + j];
      xb[j] = reinterpret_cast<const float4*>(xh)[n0 + j];
    }
#pragma unroll
    for (int r = 0; r < 4; ++r) {
      const float4 pvr = reinterpret_cast<const float4*>(Brf + (size_t)(row0 + r) * NN)[q * 256 + i4 * 64 + lane];
      const float4 pvi = reinterpret_cast<const float4*>(Bif + (size_t)(row0 + r) * NN)[q * 256 + i4 * 64 + lane];
      float* a = acc[r];
      CFMA(a, pvr.x, pvi.x, xa[0], xb[0]);
      CFMA(a, pvr.y, pvi.y, xa[1], xb[1]);
      CFMA(a, pvr.z, pvi.z, xa[2], xb[2]);
      CFMA(a, pvr.w, pvi.w, xa[3], xb[3]);
    }
  }
#undef CFMA
  float t0 = acc[0][0], t1 = acc[0][1], t2 = acc[0][2], t3 = acc[0][3];
  float t4 = acc[0][4], t5 = acc[0][5], t6 = acc[0][6], t7 = acc[0][7];
  float t8 = acc[1][0], t9 = acc[1][1], t10 = acc[1][2], t11 = acc[1][3];
  float t12 = acc[1][4], t13 = acc[1][5], t14 = acc[1][6], t15 = acc[1][7];
  float t16 = acc[2][0], t17 = acc[2][1], t18 = acc[2][2], t19 = acc[2][3];
  float t20 = acc[2][4], t21 = acc[2][5], t22 = acc[2][6], t23 = acc[2][7];
  float t24 = acc[3][0], t25 = acc[3][1], t26 = acc[3][2], t27 = acc[3][3];
  float t28 = acc[3][4], t29 = acc[3][5], t30 = acc[3][6], t31 = acc[3][7];
#define RSTEP(LO, HI, M)                                          \
  { float s_ = up ? LO : HI;                                      \
    s_ = __shfl_xor(s_, M, 64);                                   \
    LO = (up ? HI : LO) + s_; }
  { const bool up = (lane & 32) != 0;
    RSTEP(t0, t16, 32)  RSTEP(t1, t17, 32)  RSTEP(t2, t18, 32)  RSTEP(t3, t19, 32)
    RSTEP(t4, t20, 32)  RSTEP(t5, t21, 32)  RSTEP(t6, t22, 32)  RSTEP(t7, t23, 32)
    RSTEP(t8, t24, 32)  RSTEP(t9, t25, 32)  RSTEP(t10, t26, 32) RSTEP(t11, t27, 32)
    RSTEP(t12, t28, 32) RSTEP(t13, t29, 32) RSTEP(t14, t30, 32) RSTEP(t15, t31, 32) }
  { const bool up = (lane & 16) != 0;
    RSTEP(t0, t8, 16)  RSTEP(t1, t9, 16)  RSTEP(t2, t10, 16) RSTEP(t3, t11, 16)
    RSTEP(t4, t12, 16) RSTEP(t5, t13, 16) RSTEP(t6, t14, 16) RSTEP(t7, t15, 16) }
  { const bool up = (lane & 8) != 0;
    RSTEP(t0, t4, 8) RSTEP(t1, t5, 8) RSTEP(t2, t6, 8) RSTEP(t3, t7, 8) }
  { const bool up = (lane & 4) != 0;
    RSTEP(t0, t2, 4) RSTEP(t1, t3, 4) }
  { const bool up = (lane & 2) != 0;
    RSTEP(t0, t1, 2) }
#undef RSTEP
  t0 += __shfl_xor(t0, 1, 64);
  if (!(lane & 1)) red[w * 32 + ((lane >> 1) & 31)] = t0;
  __syncthreads();
  if (tid < 128) {
    int rg2 = tid >> 5, v = tid & 31;
    float s = red[(rg2 * 4 + 0) * 32 + v] + red[(rg2 * 4 + 1) * 32 + v] +
              red[(rg2 * 4 + 2) * 32 + v] + red[(rg2 * 4 + 3) * 32 + v];
    int r = v >> 3, c = v & 7, b = c >> 1, ri = c & 1;
    int m = blockIdx.x * MROWS + rg2 * 4 + r;
    float om = omega[b * NN + m];
    const float* xs = (b < 2) ? xl : xh;
    float xr = xs[m * 4 + (b & 1) * 2];
    float xi = xs[m * 4 + (b & 1) * 2 + 1];
    s += (ri == 0) ? (-om * xi) : (om * xr);
    reinterpret_cast<float*>(stNext)[(b * NN + m) * 2 + ri] = s;
    if (ri == 0) outRe[b * NN + m] = s;
  }
}

// ---------- host ----------
extern "C" void kernel_launch(void* const* d_in, const int* in_sizes, int n_in,
                              void* d_out, int out_size, void* d_ws, size_t ws_size,
                              hipStream_t stream) {
  const float* B_real = (const float*)d_in[0];
  const float* B_imag = (const float*)d_in[1];
  const float* omega  = (const float*)d_in[2];
  const float* ang    = (const float*)d_in[3];
  float* out = (float*)d_out;

  int NT = out_size / (BB * NN);                                 // 256
  const size_t planeBytes = (size_t)NN * NN * 2;                 // 32 MB
  const size_t xringBytes = (size_t)RING * XSZ * 2;              // 1 MB
  const bool coop = ws_size >= 2 * planeBytes + xringBytes;

  hipError_t launched = hipErrorUnknown;
  if (coop) {
    uint16_t* Brb   = (uint16_t*)d_ws;
    uint16_t* Bib   = Brb + (size_t)NN * NN;
    uint16_t* xring = (uint16_t*)((char*)d_ws + 2 * planeBytes);

    (void)hipMemsetAsync((void*)xring, 0xFF, xringBytes, stream);   // poison ring
    pack_planes<<<NN * NN / 8 / 256, 256, 0, stream>>>(B_real, B_imag,
                                                       (uint4*)Brb, (uint4*)Bib);

    const size_t shmem = 131072 + (size_t)8 * 16 * REDS * 4;     // 139776 B
    (void)hipFuncSetAttribute((const void*)&rnn_persistent,
                              hipFuncAttributeMaxDynamicSharedMemorySize, (int)shmem);

    void* kargs[7];
    kargs[0] = (void*)&Brb;
    kargs[1] = (void*)&Bib;
    kargs[2] = (void*)&omega;
    kargs[3] = (void*)&ang;
    kargs[4] = (void*)&xring;
    kargs[5] = (void*)&out;
    kargs[6] = (void*)&NT;
    launched = hipLaunchCooperativeKernel((const void*)&rnn_persistent,
                                          dim3(NBLK), dim3(TPB),
                                          kargs, (unsigned int)shmem, stream);
  }

  if (launched != hipSuccess) {
    // fallback: per-step launches, fp32 B from inputs, state ping-pong in ws
    float2* st0 = (float2*)d_ws;
    float2* st1 = st0 + BB * NN;
    const size_t shmemF = (size_t)(NN * 8 + 16 * 32) * sizeof(float);
    (void)hipFuncSetAttribute((const void*)&step_fb,
                              hipFuncAttributeMaxDynamicSharedMemorySize, (int)shmemF);
    init_kernel<<<(BB * NN + 255) / 256, 256, 0, stream>>>(ang, st0, out);
    for (int t = 1; t < NT; ++t) {
      float2* sp = ((t - 1) & 1) ? st1 : st0;
      float2* sn = (t & 1) ? st1 : st0;
      float* outT = out + (size_t)t * BB * NN;
      step_fb<<<NN / MROWS, 1024, shmemF, stream>>>(B_real, B_imag, omega, sp, sn, outT);
    }
  }
}

// Round 21
// 2321.593 us; speedup vs baseline: 1.6422x; 1.6422x over previous
//
#include <hip/hip_runtime.h>
#include <stdint.h>

#define NN 4096
#define BB 4
#define MROWS 16        // rows per block
#define TPB 512         // 8 waves
#define NBLK 256        // grid (1 block/CU)
#define REDS 17         // padded red row stride (dwords)
#define RING 16         // x-state ring depth (first-touch freshness)
#define XSZ  (8 * NN)   // u16 elements per ring slot (8 planes x NN)
#define EPOCH_OFF (256 * 32)   // dword offset of epoch line in flags buffer

typedef __attribute__((ext_vector_type(8))) short bf16x8;   // 8 bf16 (4 regs)
typedef __attribute__((ext_vector_type(4))) float f32x4;    // MFMA C/D

// ---------- bf16 round-to-nearest-even ----------
__device__ __forceinline__ uint32_t bf16rne(float f) {
  uint32_t u = __float_as_uint(f);
  return (u + 0x7FFFu + ((u >> 16) & 1u)) >> 16;
}

// ---------- pack B fp32 -> two row-major bf16 planes (32 MB each) ----------
__global__ void pack_planes(const float* __restrict__ Br, const float* __restrict__ Bi,
                            uint4* __restrict__ Brb, uint4* __restrict__ Bib) {
  int i = blockIdx.x * blockDim.x + threadIdx.x;     // over N*N/8
  const float4* r4 = reinterpret_cast<const float4*>(Br) + (size_t)i * 2;
  const float4* m4 = reinterpret_cast<const float4*>(Bi) + (size_t)i * 2;
  float4 a0 = r4[0], a1 = r4[1];
  float4 b0 = m4[0], b1 = m4[1];
  uint4 o;
  o.x = bf16rne(a0.x) | (bf16rne(a0.y) << 16);
  o.y = bf16rne(a0.z) | (bf16rne(a0.w) << 16);
  o.z = bf16rne(a1.x) | (bf16rne(a1.y) << 16);
  o.w = bf16rne(a1.z) | (bf16rne(a1.w) << 16);
  Brb[i] = o;
  o.x = bf16rne(b0.x) | (bf16rne(b0.y) << 16);
  o.y = bf16rne(b0.z) | (bf16rne(b0.w) << 16);
  o.z = bf16rne(b1.x) | (bf16rne(b1.y) << 16);
  o.w = bf16rne(b1.z) | (bf16rne(b1.w) << 16);
  Bib[i] = o;
}

// ============================================================================
// Persistent kernel (round-17 structure, proven 2363 us). Changes:
//  (1) Bi fragment loads for step t issued at LOOP TOP, before the sync wait
//      -> their L2 latency hides under the ~6 us spin (off critical path).
//  (2) out[] HBM store moved AFTER the flag publish (no on-device consumer).
//  (3) slot t-3 re-poison... n/a (flag protocol; kept r17 ring, no poison).
// Sync/transport identical to r17: tree flags, relaxed-agent stores, normal
// cached x loads with first-touch freshness via the 16-deep ring.
// Fragment maps identical to rounds 10-19 (verified, absmax 0.0039).
// ============================================================================
__global__ __launch_bounds__(TPB, 2)
void rnn_persistent(const uint16_t* __restrict__ Brb,
                    const uint16_t* __restrict__ Bib,
                    const float* __restrict__ omega,
                    const float* __restrict__ ang,
                    uint16_t* __restrict__ xring,  // RING * XSZ u16
                    uint32_t* __restrict__ flags,  // done[256*32] + epoch, zeroed
                    float* __restrict__ out,
                    int NT) {
  extern __shared__ char smem[];
  uint4* BrL = (uint4*)smem;                       // 16 rows * 512 slots = 128 KB
  float* red = (float*)(smem + 131072);            // 8*16*REDS fp32 = 8704 B

  const int tid  = threadIdx.x;
  const int w    = tid >> 6;       // 0..7, k-window of 512 nodes
  const int lane = tid & 63;
  const int al   = lane & 15;
  const int kq   = lane >> 4;
  const int row0 = blockIdx.x * MROWS;
  const int bid  = blockIdx.x;
  const int p1   = al & 7;
  const int p2   = p1 ^ 1;
  const int swz  = al & 7;
  const uint64_t sm64 = (al & 1) ? 0ull : 0x8000800080008000ull;  // negate -xi (even cols)

  // ---- stage Br slice into LDS, swizzled: phys = row*512 + (u ^ (row&7)) ----
  for (int j = tid; j < MROWS * 512; j += TPB) {
    int row = j >> 9;
    int u   = j & 511;
    uint4 v = *(const uint4*)(Brb + (size_t)(row0 + row) * NN + u * 8);
    BrL[row * 512 + (u ^ (row & 7))] = v;
  }

  // ---- t=0: x0 = exp(i*theta); diag regs; out[0]; ring slot 0 ----
  float myval = 0.f, om = 0.f;
  int bb = 0, mm = 0, ri = 0, cc = 0;
  if (tid < 128) {
    int r = tid >> 3; cc = tid & 7;
    mm = row0 + r; bb = cc >> 1; ri = cc & 1;
    om = omega[bb * NN + mm];
    float sv, cv;
    sincosf(ang[bb * NN + mm], &sv, &cv);
    myval = ri ? sv : cv;
    if (!ri) out[bb * NN + mm] = myval;
    float s2 = __shfl(myval, (lane + 8) & 63, 64);     // partner (r+1, same c)
    if (!((tid >> 3) & 1)) {                            // even r: pack node pair
      uint32_t pk = bf16rne(myval) | (bf16rne(s2) << 16);
      uint32_t* dst = (uint32_t*)xring + ((cc * NN + mm) >> 1);
      __hip_atomic_store(dst, pk, __ATOMIC_RELAXED, __HIP_MEMORY_SCOPE_AGENT);
    }
  }
  __syncthreads();                                     // drain stores + LDS writes
  if (tid == 0)
    __hip_atomic_store(&flags[bid * 32], 1u, __ATOMIC_RELAXED, __HIP_MEMORY_SCOPE_AGENT);

  const int nb = w * 512 + kq * 8;                     // lane's k-window base
  const uint16_t* birow = Bib + (size_t)(row0 + al) * NN + nb;

  for (int t = 1; t < NT; ++t) {
    // ---- (1) prefetch Bi fragments NOW; they fill during the sync wait ----
    bf16x8 FI0  = *(const bf16x8*)(birow +   0);
    bf16x8 FI1  = *(const bf16x8*)(birow +  32);
    bf16x8 FI2  = *(const bf16x8*)(birow +  64);
    bf16x8 FI3  = *(const bf16x8*)(birow +  96);
    bf16x8 FI4  = *(const bf16x8*)(birow + 128);
    bf16x8 FI5  = *(const bf16x8*)(birow + 160);
    bf16x8 FI6  = *(const bf16x8*)(birow + 192);
    bf16x8 FI7  = *(const bf16x8*)(birow + 224);
    bf16x8 FI8  = *(const bf16x8*)(birow + 256);
    bf16x8 FI9  = *(const bf16x8*)(birow + 288);
    bf16x8 FI10 = *(const bf16x8*)(birow + 320);
    bf16x8 FI11 = *(const bf16x8*)(birow + 352);
    bf16x8 FI12 = *(const bf16x8*)(birow + 384);
    bf16x8 FI13 = *(const bf16x8*)(birow + 416);
    bf16x8 FI14 = *(const bf16x8*)(birow + 448);
    bf16x8 FI15 = *(const bf16x8*)(birow + 480);

    // ---- tree sync: step t-1 data visible everywhere before compute ----
    if (bid == 0) {
      if (tid < 256) {                                 // one line per lane
        const uint32_t want = (uint32_t)t;
        for (int spin = 0; spin < (1 << 22); ++spin) {
          uint32_t f = __hip_atomic_load(&flags[tid * 32],
                                         __ATOMIC_RELAXED, __HIP_MEMORY_SCOPE_AGENT);
          if (f >= want) break;
          __builtin_amdgcn_s_sleep(1);
        }
      }
      __syncthreads();
      if (tid == 0)
        __hip_atomic_store(&flags[EPOCH_OFF], (uint32_t)t,
                           __ATOMIC_RELAXED, __HIP_MEMORY_SCOPE_AGENT);
    } else {
      if (tid == 0) {                                  // poll single epoch line
        const uint32_t want = (uint32_t)t;
        for (int spin = 0; spin < (1 << 22); ++spin) {
          uint32_t e = __hip_atomic_load(&flags[EPOCH_OFF],
                                         __ATOMIC_RELAXED, __HIP_MEMORY_SCOPE_AGENT);
          if (e >= want) break;
          __builtin_amdgcn_s_sleep(1);
        }
      }
      __syncthreads();
    }

    const uint16_t* xs = xring + (size_t)((t - 1) & (RING - 1)) * XSZ;
    f32x4 accA = {0.f, 0.f, 0.f, 0.f};
    f32x4 accB = {0.f, 0.f, 0.f, 0.f};

#define SSTEP(S, FI)                                                            \
    { union { uint4 q; bf16x8 v; } fr;                                         \
      fr.q = BrL[al * 512 + (((S) == -1 ? 0 : ((w << 6) + ((S) << 2) + kq)) ^ swz)]; \
      const uint16_t* x1p = xs + p1 * NN + nb + (S) * 32;                       \
      const uint16_t* x2p = xs + p2 * NN + nb + (S) * 32;                       \
      union { uint64_t q[2]; bf16x8 v; } u1, u2;                                \
      u1.q[0] = *(const uint64_t*)(x1p);                                        \
      u1.q[1] = *(const uint64_t*)(x1p + 4);                                    \
      u2.q[0] = *(const uint64_t*)(x2p) ^ sm64;                                 \
      u2.q[1] = *(const uint64_t*)(x2p + 4) ^ sm64;                             \
      accA = __builtin_amdgcn_mfma_f32_16x16x32_bf16(fr.v, u1.v, accA, 0, 0, 0);\
      accB = __builtin_amdgcn_mfma_f32_16x16x32_bf16(FI,   u2.v, accB, 0, 0, 0); }
    SSTEP(0,  FI0)  SSTEP(1,  FI1)  SSTEP(2,  FI2)  SSTEP(3,  FI3)
    SSTEP(4,  FI4)  SSTEP(5,  FI5)  SSTEP(6,  FI6)  SSTEP(7,  FI7)
    SSTEP(8,  FI8)  SSTEP(9,  FI9)  SSTEP(10, FI10) SSTEP(11, FI11)
    SSTEP(12, FI12) SSTEP(13, FI13) SSTEP(14, FI14) SSTEP(15, FI15)
#undef SSTEP

    // ---- partial tiles -> padded LDS ----
    {
      float* rw = red + w * 16 * REDS;
      rw[(kq * 4 + 0) * REDS + al] = accA[0] + accB[0];
      rw[(kq * 4 + 1) * REDS + al] = accA[1] + accB[1];
      rw[(kq * 4 + 2) * REDS + al] = accA[2] + accB[2];
      rw[(kq * 4 + 3) * REDS + al] = accA[3] + accB[3];
    }
    __syncthreads();

    // ---- cross-wave sum + diagonal + x-ring store (critical path only) ----
    if (tid < 128) {
      int r = tid >> 3;
      float s = 0.f;
#pragma unroll
      for (int w2 = 0; w2 < 8; ++w2) s += red[w2 * 16 * REDS + r * REDS + cc];
      float other = __shfl_xor(myval, 1, 64);
      float xr = ri ? other : myval;
      float xi = ri ? myval : other;
      // i*omega*(xr + i*xi) = -omega*xi + i*omega*xr
      s += ri ? (om * xr) : (-om * xi);
      myval = s;                                       // fp32 diag chain in reg
      float s2 = __shfl(s, (lane + 8) & 63, 64);       // partner (r+1, same c)
      if (!((tid >> 3) & 1)) {
        uint32_t pk = bf16rne(s) | (bf16rne(s2) << 16);
        uint32_t* dst = (uint32_t*)(xring + (size_t)(t & (RING - 1)) * XSZ)
                        + ((cc * NN + mm) >> 1);
        __hip_atomic_store(dst, pk, __ATOMIC_RELAXED, __HIP_MEMORY_SCOPE_AGENT);
      }
    }
    __syncthreads();                                   // drain x stores (vmcnt 0)
    if (tid == 0)
      __hip_atomic_store(&flags[bid * 32], (uint32_t)(t + 1),
                         __ATOMIC_RELAXED, __HIP_MEMORY_SCOPE_AGENT);

    // ---- (2) off-critical-path: out[] HBM store AFTER the flag publish ----
    if (tid < 128 && !ri)
      out[(size_t)t * (BB * NN) + bb * NN + mm] = myval;
  }
}

// ============================================================================
// Fallback (fp32 B direct, per-step launches) — only if coop launch fails.
// ============================================================================
__global__ void init_kernel(const float* __restrict__ ang,
                            float2* __restrict__ st0, float* __restrict__ out0) {
  int i = blockIdx.x * blockDim.x + threadIdx.x;
  if (i < BB * NN) {
    float s, c;
    sincosf(ang[i], &s, &c);
    st0[i] = make_float2(c, s);
    out0[i] = c;
  }
}

__global__ __launch_bounds__(1024)
void step_fb(const float* __restrict__ Brf, const float* __restrict__ Bif,
             const float* __restrict__ omega,
             const float2* __restrict__ stPrev, float2* __restrict__ stNext,
             float* __restrict__ outRe) {
  extern __shared__ float lds[];
  float* xl  = lds;
  float* xh  = lds + NN * 4;
  float* red = lds + NN * 8;
  const int tid = threadIdx.x;
#pragma unroll
  for (int k = 0; k < 8; ++k) {
    int idx = tid + k * 1024;
    int half = idx >> 12;
    int n = idx & (NN - 1);
    float2 v0 = stPrev[(half * 2) * NN + n];
    float2 v1 = stPrev[(half * 2 + 1) * NN + n];
    reinterpret_cast<float4*>(half ? xh : xl)[n] = make_float4(v0.x, v0.y, v1.x, v1.y);
  }
  __syncthreads();
  const int w = tid >> 6, lane = tid & 63, rg = w >> 2, q = w & 3;
  const int row0 = blockIdx.x * MROWS + rg * 4;
  float acc[4][8];
#pragma unroll
  for (int r = 0; r < 4; ++r)
#pragma unroll
    for (int c = 0; c < 8; ++c) acc[r][c] = 0.0f;
#define CFMA(A, BR, BI, XA, XB)                                   \
  A[0] = fmaf(BR, XA.x, A[0]); A[0] = fmaf(-BI, XA.y, A[0]);      \
  A[1] = fmaf(BR, XA.y, A[1]); A[1] = fmaf(BI, XA.x, A[1]);       \
  A[2] = fmaf(BR, XA.z, A[2]); A[2] = fmaf(-BI, XA.w, A[2]);      \
  A[3] = fmaf(BR, XA.w, A[3]); A[3] = fmaf(BI, XA.z, A[3]);       \
  A[4] = fmaf(BR, XB.x, A[4]); A[4] = fmaf(-BI, XB.y, A[4]);      \
  A[5] = fmaf(BR, XB.y, A[5]); A[5] = fmaf(BI, XB.x, A[5]);       \
  A[6] = fmaf(BR, XB.z, A[6]); A[6] = fmaf(-BI, XB.w, A[6]);      \
  A[7] = fmaf(BR, XB.w, A[7]); A[7] = fmaf(BI, XB.z, A[7]);
  for (int i4 = 0; i4 < 4; ++i4) {
    const int n0 = q * 1024 + i4 * 256 + lane * 4;
    float4 xa[4], xb[4];
#pragma unroll
    for (int j = 0; j < 4; ++j) {
      xa[j] = reinterpret_cast<const float4*>(xl)[n0 + j];
      xb[j] = reinterpret_cast<const float4*>(xh)[n0 + j];
    }
#pragma unroll
    for (int r = 0; r < 4; ++r) {
      const float4 pvr = reinterpret_cast<const float4*>(Brf + (size_t)(row0 + r) * NN)[q * 256 + i4 * 64 + lane];
      const float4 pvi = reinterpret_cast<const float4*>(Bif + (size_t)(row0 + r) * NN)[q * 256 + i4 * 64 + lane];
      float* a = acc[r];
      CFMA(a, pvr.x, pvi.x, xa[0], xb[0]);
      CFMA(a, pvr.y, pvi.y, xa[1], xb[1]);
      CFMA(a, pvr.z, pvi.z, xa[2], xb[2]);
      CFMA(a, pvr.w, pvi.w, xa[3], xb[3]);
    }
  }
#undef CFMA
  float t0 = acc[0][0], t1 = acc[0][1], t2 = acc[0][2], t3 = acc[0][3];
  float t4 = acc[0][4], t5 = acc[0][5], t6 = acc[0][6], t7 = acc[0][7];
  float t8 = acc[1][0], t9 = acc[1][1], t10 = acc[1][2], t11 = acc[1][3];
  float t12 = acc[1][4], t13 = acc[1][5], t14 = acc[1][6], t15 = acc[1][7];
  float t16 = acc[2][0], t17 = acc[2][1], t18 = acc[2][2], t19 = acc[2][3];
  float t20 = acc[2][4], t21 = acc[2][5], t22 = acc[2][6], t23 = acc[2][7];
  float t24 = acc[3][0], t25 = acc[3][1], t26 = acc[3][2], t27 = acc[3][3];
  float t28 = acc[3][4], t29 = acc[3][5], t30 = acc[3][6], t31 = acc[3][7];
#define RSTEP(LO, HI, M)                                          \
  { float s_ = up ? LO : HI;                                      \
    s_ = __shfl_xor(s_, M, 64);                                   \
    LO = (up ? HI : LO) + s_; }
  { const bool up = (lane & 32) != 0;
    RSTEP(t0, t16, 32)  RSTEP(t1, t17, 32)  RSTEP(t2, t18, 32)  RSTEP(t3, t19, 32)
    RSTEP(t4, t20, 32)  RSTEP(t5, t21, 32)  RSTEP(t6, t22, 32)  RSTEP(t7, t23, 32)
    RSTEP(t8, t24, 32)  RSTEP(t9, t25, 32)  RSTEP(t10, t26, 32) RSTEP(t11, t27, 32)
    RSTEP(t12, t28, 32) RSTEP(t13, t29, 32) RSTEP(t14, t30, 32) RSTEP(t15, t31, 32) }
  { const bool up = (lane & 16) != 0;
    RSTEP(t0, t8, 16)  RSTEP(t1, t9, 16)  RSTEP(t2, t10, 16) RSTEP(t3, t11, 16)
    RSTEP(t4, t12, 16) RSTEP(t5, t13, 16) RSTEP(t6, t14, 16) RSTEP(t7, t15, 16) }
  { const bool up = (lane & 8) != 0;
    RSTEP(t0, t4, 8) RSTEP(t1, t5, 8) RSTEP(t2, t6, 8) RSTEP(t3, t7, 8) }
  { const bool up = (lane & 4) != 0;
    RSTEP(t0, t2, 4) RSTEP(t1, t3, 4) }
  { const bool up = (lane & 2) != 0;
    RSTEP(t0, t1, 2) }
#undef RSTEP
  t0 += __shfl_xor(t0, 1, 64);
  if (!(lane & 1)) red[w * 32 + ((lane >> 1) & 31)] = t0;
  __syncthreads();
  if (tid < 128) {
    int rg2 = tid >> 5, v = tid & 31;
    float s = red[(rg2 * 4 + 0) * 32 + v] + red[(rg2 * 4 + 1) * 32 + v] +
              red[(rg2 * 4 + 2) * 32 + v] + red[(rg2 * 4 + 3) * 32 + v];
    int r = v >> 3, c = v & 7, b = c >> 1, ri = c & 1;
    int m = blockIdx.x * MROWS + rg2 * 4 + r;
    float om = omega[b * NN + m];
    const float* xs = (b < 2) ? xl : xh;
    float xr = xs[m * 4 + (b & 1) * 2];
    float xi = xs[m * 4 + (b & 1) * 2 + 1];
    s += (ri == 0) ? (-om * xi) : (om * xr);
    reinterpret_cast<float*>(stNext)[(b * NN + m) * 2 + ri] = s;
    if (ri == 0) outRe[b * NN + m] = s;
  }
}

// ---------- host ----------
extern "C" void kernel_launch(void* const* d_in, const int* in_sizes, int n_in,
                              void* d_out, int out_size, void* d_ws, size_t ws_size,
                              hipStream_t stream) {
  const float* B_real = (const float*)d_in[0];
  const float* B_imag = (const float*)d_in[1];
  const float* omega  = (const float*)d_in[2];
  const float* ang    = (const float*)d_in[3];
  float* out = (float*)d_out;

  int NT = out_size / (BB * NN);                                 // 256
  const size_t planeBytes = (size_t)NN * NN * 2;                 // 32 MB
  const size_t xringBytes = (size_t)RING * XSZ * 2;              // 1 MB
  const size_t flagBytes  = (256 * 32 + 32) * sizeof(uint32_t);  // done[] + epoch
  const bool coop = ws_size >= 2 * planeBytes + xringBytes + flagBytes;

  hipError_t launched = hipErrorUnknown;
  if (coop) {
    uint16_t* Brb   = (uint16_t*)d_ws;
    uint16_t* Bib   = Brb + (size_t)NN * NN;
    uint16_t* xring = (uint16_t*)((char*)d_ws + 2 * planeBytes);
    uint32_t* flags = (uint32_t*)((char*)d_ws + 2 * planeBytes + xringBytes);

    (void)hipMemsetAsync((void*)flags, 0, flagBytes, stream);    // flags -> 0
    pack_planes<<<NN * NN / 8 / 256, 256, 0, stream>>>(B_real, B_imag,
                                                       (uint4*)Brb, (uint4*)Bib);

    const size_t shmem = 131072 + (size_t)8 * 16 * REDS * 4;     // 139776 B
    (void)hipFuncSetAttribute((const void*)&rnn_persistent,
                              hipFuncAttributeMaxDynamicSharedMemorySize, (int)shmem);

    void* kargs[8];
    kargs[0] = (void*)&Brb;
    kargs[1] = (void*)&Bib;
    kargs[2] = (void*)&omega;
    kargs[3] = (void*)&ang;
    kargs[4] = (void*)&xring;
    kargs[5] = (void*)&flags;
    kargs[6] = (void*)&out;
    kargs[7] = (void*)&NT;
    launched = hipLaunchCooperativeKernel((const void*)&rnn_persistent,
                                          dim3(NBLK), dim3(TPB),
                                          kargs, (unsigned int)shmem, stream);
  }

  if (launched != hipSuccess) {
    // fallback: per-step launches, fp32 B from inputs, state ping-pong in ws
    float2* st0 = (float2*)d_ws;
    float2* st1 = st0 + BB * NN;
    const size_t shmemF = (size_t)(NN * 8 + 16 * 32) * sizeof(float);
    (void)hipFuncSetAttribute((const void*)&step_fb,
                              hipFuncAttributeMaxDynamicSharedMemorySize, (int)shmemF);
    init_kernel<<<(BB * NN + 255) / 256, 256, 0, stream>>>(ang, st0, out);
    for (int t = 1; t < NT; ++t) {
      float2* sp = ((t - 1) & 1) ? st1 : st0;
      float2* sn = (t & 1) ? st1 : st0;
      float* outT = out + (size_t)t * BB * NN;
      step_fb<<<NN / MROWS, 1024, shmemF, stream>>>(B_real, B_imag, omega, sp, sn, outT);
    }
  }
}